// Round 2
// baseline (370.198 us; speedup 1.0000x reference)
//
#include <hip/hip_runtime.h>
#include <math.h>

#define NT 16384
#define D 4096
#define NE 128
#define NSPLIT 4
#define KS (D / NSPLIT)   // 1024
#define BK 32
#define NCH (KS / BK)     // 32
#define BM 128
#define INV_T (1.0f / 0.07f)
#define TAU 3e-6f
#define FIXCAP 4096

typedef _Float16 h16;
typedef _Float16 h8 __attribute__((ext_vector_type(8)));
typedef _Float16 h4 __attribute__((ext_vector_type(4)));
typedef float f4 __attribute__((ext_vector_type(4)));

// ---- static device scratch (avoids ws_size assumptions; fully rewritten each call) ----
__device__ float g_S[NSPLIT][NT][NE];    // 32 MB raw-dot partials
__device__ float g_ssq[NSPLIT][NT];      // per-token |x|^2 partials
__device__ float g_wgn[NE * D];          // normalized W, fp32 (for fixup)
__device__ h16   g_whi[NE * D];          // fp16 hi split of normalized W
__device__ h16   g_wlo[NE * D];          // fp16 lo split
__device__ int   g_tte[NT];
__device__ int   g_cnt;
__device__ int   g_flag[FIXCAP];
__device__ float g_me[256][NE];          // per-epi-block softmax column sums
__device__ int   g_hist[NT / 256][NE];
__device__ int   g_pos[NT / 256][NE];

// LDS XOR slot swizzle for [row][32 h16] tiles (64B rows, 16B slots)
__device__ __forceinline__ int swz(int r, int s) {
    return r * 64 + (((s ^ (r & 3) ^ ((r >> 2) & 3) ^ ((r >> 4) & 1)) & 3) << 4);
}

// ---------------- kernel 1: normalize W (fp32) + fp16 hi/lo split -------------
__global__ __launch_bounds__(256) void k_prep(const float* __restrict__ wg) {
    int e = blockIdx.x;
    int tid = threadIdx.x;
    if (e == 0 && tid == 0) g_cnt = 0;
    const f4* row = (const f4*)(wg + (size_t)e * D);
    float ss = 0.f;
    f4 v[4];
    #pragma unroll
    for (int c = 0; c < 4; c++) {
        v[c] = row[tid + 256 * c];
        ss += v[c][0]*v[c][0] + v[c][1]*v[c][1] + v[c][2]*v[c][2] + v[c][3]*v[c][3];
    }
    __shared__ float red[4];
    #pragma unroll
    for (int o = 32; o > 0; o >>= 1) ss += __shfl_xor(ss, o, 64);
    if ((tid & 63) == 0) red[tid >> 6] = ss;
    __syncthreads();
    float den = fmaxf(sqrtf(red[0] + red[1] + red[2] + red[3]), 1e-4f);
    #pragma unroll
    for (int c = 0; c < 4; c++) {
        size_t base = (size_t)e * D + (size_t)(tid + 256 * c) * 4;
        f4 wn;
        h4 hi, lo;
        #pragma unroll
        for (int k = 0; k < 4; k++) {
            wn[k] = v[c][k] / den;
            hi[k] = (h16)wn[k];
            lo[k] = (h16)(wn[k] - (float)hi[k]);
        }
        *(f4*)(g_wgn + base) = wn;
        *(h4*)(g_whi + base) = hi;
        *(h4*)(g_wlo + base) = lo;
    }
}

// ---------------- kernel 2: fp16x3 MFMA split-K GEMM --------------------------
// grid 512 = 128 token-blocks x 4 k-slices; 256 threads (4 waves, 2x2 wave grid)
__global__ __launch_bounds__(256, 2) void k_mfma(const float* __restrict__ x) {
    __shared__ __align__(16) char smem[2][32768];  // [buf][x_hi|x_lo|w_hi|w_lo] 8KB planes

    const int tid = threadIdx.x;
    const int bid = blockIdx.x;
    const int tb = bid & 127;
    const int slice = bid >> 7;
    const int t0 = tb * BM;
    const int kb0 = slice * KS;

    // staging roles
    const int xr = tid >> 1, xh = tid & 1;        // x: 2 threads/row, 16 floats each
    const int wp = tid >> 7, wrw = tid & 127;     // w: plane (hi/lo), row
    const float* xg = x + (size_t)(t0 + xr) * D + kb0 + xh * 16;
    const h16* wgp = (wp ? g_wlo : g_whi) + (size_t)wrw * D + kb0;

    // compute roles
    const int wid = tid >> 6;
    const int wr = (wid >> 1) * 64, wc = (wid & 1) * 64;
    const int lane = tid & 63;
    const int lrow = lane & 15, lslot = lane >> 4;

    f4 acc[4][4];
    #pragma unroll
    for (int i = 0; i < 4; i++)
        #pragma unroll
        for (int j = 0; j < 4; j++) acc[i][j] = (f4)0.0f;
    float ssq = 0.f;

    f4 xv[4];
    uint4 wv[4];

#define LOADC(c) do { \
        const f4* xp = (const f4*)(xg + (c) * BK); \
        xv[0] = xp[0]; xv[1] = xp[1]; xv[2] = xp[2]; xv[3] = xp[3]; \
        const uint4* wq = (const uint4*)(wgp + (c) * BK); \
        wv[0] = wq[0]; wv[1] = wq[1]; wv[2] = wq[2]; wv[3] = wq[3]; \
    } while (0)

#define STOREC(b) do { \
        char* s_ = smem[b]; \
        _Pragma("unroll") \
        for (int g = 0; g < 2; g++) { \
            f4 a_ = xv[2*g], b_ = xv[2*g+1]; \
            ssq += a_[0]*a_[0] + a_[1]*a_[1] + a_[2]*a_[2] + a_[3]*a_[3] \
                 + b_[0]*b_[0] + b_[1]*b_[1] + b_[2]*b_[2] + b_[3]*b_[3]; \
            h8 hi_, lo_; \
            _Pragma("unroll") \
            for (int k = 0; k < 4; k++) { \
                hi_[k]   = (h16)a_[k]; lo_[k]   = (h16)(a_[k] - (float)hi_[k]); \
                hi_[k+4] = (h16)b_[k]; lo_[k+4] = (h16)(b_[k] - (float)hi_[k+4]); \
            } \
            int off_ = swz(xr, 2*xh + g); \
            *(h8*)(s_ + off_)        = hi_; \
            *(h8*)(s_ + 8192 + off_) = lo_; \
        } \
        _Pragma("unroll") \
        for (int q = 0; q < 4; q++) \
            *(uint4*)(s_ + 16384 + wp*8192 + swz(wrw, q)) = wv[q]; \
    } while (0)

#define COMPUTEC(b) do { \
        char* s_ = smem[b]; \
        h8 ah[4], al[4], bh[4], bl[4]; \
        _Pragma("unroll") \
        for (int i = 0; i < 4; i++) { \
            int off_ = swz(wr + i*16 + lrow, lslot); \
            ah[i] = *(const h8*)(s_ + off_); \
            al[i] = *(const h8*)(s_ + 8192 + off_); \
        } \
        _Pragma("unroll") \
        for (int j = 0; j < 4; j++) { \
            int off_ = swz(wc + j*16 + lrow, lslot); \
            bh[j] = *(const h8*)(s_ + 16384 + off_); \
            bl[j] = *(const h8*)(s_ + 24576 + off_); \
        } \
        _Pragma("unroll") \
        for (int i = 0; i < 4; i++) \
            _Pragma("unroll") \
            for (int j = 0; j < 4; j++) { \
                acc[i][j] = __builtin_amdgcn_mfma_f32_16x16x32_f16(ah[i], bh[j], acc[i][j], 0, 0, 0); \
                acc[i][j] = __builtin_amdgcn_mfma_f32_16x16x32_f16(ah[i], bl[j], acc[i][j], 0, 0, 0); \
                acc[i][j] = __builtin_amdgcn_mfma_f32_16x16x32_f16(al[i], bh[j], acc[i][j], 0, 0, 0); \
            } \
    } while (0)

    LOADC(0);
    STOREC(0);
    __syncthreads();
    int buf = 0;
    for (int c = 0; c < NCH; ++c) {
        if (c + 1 < NCH) LOADC(c + 1);     // issue next global loads early
        COMPUTEC(buf);                     // ds_read + MFMA hide the load latency
        if (c + 1 < NCH) STOREC(buf ^ 1);  // vmcnt wait lands here, after compute
        __syncthreads();
        buf ^= 1;
    }

    // per-token |x|^2 partial (2 staging threads per row)
    ssq += __shfl_xor(ssq, 1, 64);
    if (xh == 0) g_ssq[slice][t0 + xr] = ssq;

    // C write: col = lane&15, row = (lane>>4)*4 + reg
    #pragma unroll
    for (int i = 0; i < 4; i++)
        #pragma unroll
        for (int j = 0; j < 4; j++)
            #pragma unroll
            for (int q = 0; q < 4; q++)
                g_S[slice][t0 + wr + i*16 + lslot*4 + q][wc + j*16 + lrow] = acc[i][j][q];
}

// ---------------- kernel 3: epilogue (reduce slices, argmax, gap, softmax) ----
// grid 256 blocks x 128 threads; 64 tokens/block, 2 threads per token
__global__ __launch_bounds__(128) void k_epi() {
    __shared__ float gsm[128][65];
    const int tid = threadIdx.x;
    const int t = blockIdx.x * 64 + (tid >> 1);
    const int h = tid & 1;

    float L[64];
    {
        const float* sp = &g_S[0][t][h * 64];
        #pragma unroll
        for (int jj = 0; jj < 16; jj++) {
            f4 v = *(const f4*)(sp + jj * 4);
            L[jj*4+0] = v[0]; L[jj*4+1] = v[1]; L[jj*4+2] = v[2]; L[jj*4+3] = v[3];
        }
    }
    #pragma unroll
    for (int s = 1; s < NSPLIT; s++) {
        const float* sp = &g_S[s][t][h * 64];
        #pragma unroll
        for (int jj = 0; jj < 16; jj++) {
            f4 v = *(const f4*)(sp + jj * 4);
            L[jj*4+0] += v[0]; L[jj*4+1] += v[1]; L[jj*4+2] += v[2]; L[jj*4+3] += v[3];
        }
    }
    float n2 = g_ssq[0][t] + g_ssq[1][t] + g_ssq[2][t] + g_ssq[3][t];
    float scl = 1.0f / fmaxf(sqrtf(n2), 1e-4f);

    float m1 = -1e30f, m2 = -1e30f;
    int a1 = h * 64;
    #pragma unroll
    for (int j = 0; j < 64; j++) {
        float v = L[j] * scl;
        L[j] = v;
        if (v > m1) { m2 = m1; m1 = v; a1 = h * 64 + j; }
        else if (v > m2) m2 = v;
    }
    float m1o = __shfl_xor(m1, 1, 64);
    int   a1o = __shfl_xor(a1, 1, 64);
    float m2o = __shfl_xor(m2, 1, 64);
    float m2g = fmaxf(fmaxf(m2, m2o), fminf(m1, m1o));
    float m1g; int a1g;
    if (m1o > m1 || (m1o == m1 && a1o < a1)) { m1g = m1o; a1g = a1o; }
    else { m1g = m1; a1g = a1; }

    if (h == 0) {
        g_tte[t] = a1g;
        if (m1g - m2g < TAU) {               // near-tie -> fp32 recheck
            int ix = atomicAdd(&g_cnt, 1);
            if (ix < FIXCAP) g_flag[ix] = t;
        }
    }

    // softmax(logits/0.07) per token; accumulate per-expert column sums
    float ssum = 0.f;
    #pragma unroll
    for (int j = 0; j < 64; j++) {
        float ex = __expf((L[j] - m1g) * INV_T);
        L[j] = ex;
        ssum += ex;
    }
    ssum += __shfl_xor(ssum, 1, 64);
    float inv = 1.0f / ssum;
    #pragma unroll
    for (int j = 0; j < 64; j++) gsm[tid][j] = L[j] * inv;
    __syncthreads();

    // column sums: expert e lives in column e&63 of rows with parity e>>6
    int e = tid;
    int col = e & 63, par = e >> 6;
    float s = 0.f;
    #pragma unroll 8
    for (int m = 0; m < 64; m++) s += gsm[2 * m + par][col];
    g_me[blockIdx.x][e] = s;
}

// ---------------- kernel 4: exact fp32 recheck of near-tie tokens -------------
__global__ __launch_bounds__(64) void k_fix(const float* __restrict__ x) {
    int n = g_cnt;
    if (n > FIXCAP) n = FIXCAP;
    const int l = threadIdx.x;
    for (int i = blockIdx.x; i < n; i += gridDim.x) {
        int t = g_flag[i];
        const float* xr = x + (size_t)t * D;
        float m1 = -1e30f;
        int a1 = 0;
        for (int e = 0; e < NE; e++) {
            const float* wr = g_wgn + (size_t)e * D;
            float s = 0.f;
            #pragma unroll 4
            for (int c = 0; c < 16; c++) {
                f4 xv = *(const f4*)(xr + c * 256 + l * 4);
                f4 wv = *(const f4*)(wr + c * 256 + l * 4);
                s = fmaf(xv[0], wv[0], s);
                s = fmaf(xv[1], wv[1], s);
                s = fmaf(xv[2], wv[2], s);
                s = fmaf(xv[3], wv[3], s);
            }
            #pragma unroll
            for (int o = 1; o < 64; o <<= 1) s += __shfl_xor(s, o, 64);
            if (s > m1) { m1 = s; a1 = e; }   // strict > ascending = first-index tie-break
        }
        if (l == 0) g_tte[t] = a1;
    }
}

// ---------------- kernel 5: per-chunk expert histograms -----------------------
__global__ __launch_bounds__(256) void k_hist() {
    __shared__ int h[NE];
    int tid = threadIdx.x;
    if (tid < NE) h[tid] = 0;
    __syncthreads();
    atomicAdd(&h[g_tte[blockIdx.x * 256 + tid]], 1);
    __syncthreads();
    if (tid < NE) g_hist[blockIdx.x][tid] = h[tid];
}

// ---------------- kernel 6: scans + l_aux + splits ----------------------------
__global__ __launch_bounds__(128) void k_scan(float* __restrict__ out) {
    __shared__ int total[NE];
    __shared__ float me[NE];
    int e = threadIdx.x;
    int run = 0;
    #pragma unroll 8
    for (int c = 0; c < NT / 256; c++) run += g_hist[c][e];
    total[e] = run;
    __syncthreads();
    int off = 0;
    for (int i = 0; i < e; i++) off += total[i];
    int p = off;
    for (int c = 0; c < NT / 256; c++) { g_pos[c][e] = p; p += g_hist[c][e]; }
    float s = 0.f;
    #pragma unroll 8
    for (int b = 0; b < 256; b++) s += g_me[b][e];
    me[e] = s;
    __syncthreads();
    if (e == 0) {
        float acc = 0.f;
        for (int i = 0; i < NE; i++)
            acc += me[i] * ((float)total[i] * (1.0f / 16384.0f) + 1e-6f);
        out[0] = acc * 128.0f;   // l_aux
    }
    out[1 + NT + e]      = (float)total[e];   // input_splits
    out[1 + NT + NE + e] = (float)total[e];   // output_splits
}

// ---------------- kernel 7: stable placement (counting sort) ------------------
__global__ __launch_bounds__(256) void k_place(float* __restrict__ out) {
    __shared__ int arr[256];
    int tid = threadIdx.x;
    int c = blockIdx.x;
    int t = c * 256 + tid;
    int e = g_tte[t];
    arr[tid] = e;
    __syncthreads();
    int rank = 0;
    for (int j = 0; j < tid; j++) rank += (arr[j] == e) ? 1 : 0;
    out[1 + g_pos[c][e] + rank] = (float)t;
}

// ---------------- launcher ----------------------------------------------------
extern "C" void kernel_launch(void* const* d_in, const int* in_sizes, int n_in,
                              void* d_out, int out_size, void* d_ws, size_t ws_size,
                              hipStream_t stream) {
    const float* x  = (const float*)d_in[0];
    const float* wg = (const float*)d_in[1];
    // d_in[2] = gating_t: sigmoid(x/temp) is monotonic -> argmax unaffected
    float* out = (float*)d_out;

    k_prep<<<NE, 256, 0, stream>>>(wg);
    k_mfma<<<128 * NSPLIT, 256, 0, stream>>>(x);
    k_epi<<<NT / 64, 128, 0, stream>>>();
    k_fix<<<256, 64, 0, stream>>>(x);
    k_hist<<<NT / 256, 256, 0, stream>>>();
    k_scan<<<1, 128, 0, stream>>>(out);
    k_place<<<NT / 256, 256, 0, stream>>>(out);
}

// Round 3
// 171.189 us; speedup vs baseline: 2.1625x; 2.1625x over previous
//
#include <hip/hip_runtime.h>
#include <math.h>

#define NT 16384
#define D 4096
#define NE 128
#define NSPLIT 4
#define KS (D / NSPLIT)   // 1024
#define BK 32
#define NCH (KS / BK)     // 32
#define BM 128
#define INV_T (1.0f / 0.07f)
#define TAU 3e-6f
#define FIXCAP 4096

typedef _Float16 h16;
typedef _Float16 h8 __attribute__((ext_vector_type(8)));
typedef _Float16 h4 __attribute__((ext_vector_type(4)));
typedef float f4 __attribute__((ext_vector_type(4)));

// ---- static device scratch (avoids ws_size assumptions; fully rewritten each call) ----
__device__ float g_S[NSPLIT][NT][NE];    // 32 MB raw-dot partials
__device__ float g_ssq[NSPLIT][NT];      // per-token |x|^2 partials
__device__ float g_wgn[NE * D];          // normalized W, fp32 (for fixup)
__device__ h16   g_whi[NE * D];          // fp16 hi split of normalized W
__device__ h16   g_wlo[NE * D];          // fp16 lo split
__device__ int   g_tte[NT];
__device__ int   g_cnt;
__device__ int   g_flag[FIXCAP];
__device__ float g_me[256][NE];          // per-epi-block softmax column sums
__device__ int   g_hist[NT / 256][NE];
__device__ int   g_pos[NT / 256][NE];

// LDS XOR slot swizzle for [row][32 h16] tiles (64B rows, 16B slots)
__device__ __forceinline__ int swz(int r, int s) {
    return r * 64 + (((s ^ (r & 3) ^ ((r >> 2) & 3) ^ ((r >> 4) & 1)) & 3) << 4);
}

// ---------------- kernel 1: normalize W (fp32) + fp16 hi/lo split -------------
__global__ __launch_bounds__(256) void k_prep(const float* __restrict__ wg) {
    int e = blockIdx.x;
    int tid = threadIdx.x;
    if (e == 0 && tid == 0) g_cnt = 0;
    const f4* row = (const f4*)(wg + (size_t)e * D);
    float ss = 0.f;
    f4 v[4];
    #pragma unroll
    for (int c = 0; c < 4; c++) {
        v[c] = row[tid + 256 * c];
        ss += v[c][0]*v[c][0] + v[c][1]*v[c][1] + v[c][2]*v[c][2] + v[c][3]*v[c][3];
    }
    __shared__ float red[4];
    #pragma unroll
    for (int o = 32; o > 0; o >>= 1) ss += __shfl_xor(ss, o, 64);
    if ((tid & 63) == 0) red[tid >> 6] = ss;
    __syncthreads();
    float den = fmaxf(sqrtf(red[0] + red[1] + red[2] + red[3]), 1e-4f);
    #pragma unroll
    for (int c = 0; c < 4; c++) {
        size_t base = (size_t)e * D + (size_t)(tid + 256 * c) * 4;
        f4 wn;
        h4 hi, lo;
        #pragma unroll
        for (int k = 0; k < 4; k++) {
            wn[k] = v[c][k] / den;
            hi[k] = (h16)wn[k];
            lo[k] = (h16)(wn[k] - (float)hi[k]);
        }
        *(f4*)(g_wgn + base) = wn;
        *(h4*)(g_whi + base) = hi;
        *(h4*)(g_wlo + base) = lo;
    }
}

// ---------------- kernel 2: fp16x3 MFMA split-K GEMM --------------------------
// grid 512 = 128 token-blocks x 4 k-slices; 256 threads (4 waves, 2x2 wave grid)
__global__ __launch_bounds__(256, 2) void k_mfma(const float* __restrict__ x) {
    __shared__ __align__(16) char smem[2][32768];  // [buf][x_hi|x_lo|w_hi|w_lo] 8KB planes

    const int tid = threadIdx.x;
    const int bid = blockIdx.x;
    const int tb = bid & 127;
    const int slice = bid >> 7;
    const int t0 = tb * BM;
    const int kb0 = slice * KS;

    // staging roles
    const int xr = tid >> 1, xh = tid & 1;        // x: 2 threads/row, 16 floats each
    const int wp = tid >> 7, wrw = tid & 127;     // w: plane (hi/lo), row
    const float* xg = x + (size_t)(t0 + xr) * D + kb0 + xh * 16;
    const h16* wgp = (wp ? g_wlo : g_whi) + (size_t)wrw * D + kb0;

    // compute roles
    const int wid = tid >> 6;
    const int wr = (wid >> 1) * 64, wc = (wid & 1) * 64;
    const int lane = tid & 63;
    const int lrow = lane & 15, lslot = lane >> 4;

    f4 acc[4][4];
    #pragma unroll
    for (int i = 0; i < 4; i++)
        #pragma unroll
        for (int j = 0; j < 4; j++) acc[i][j] = (f4)0.0f;
    float ssq = 0.f;

    f4 xv[4];
    uint4 wv[4];

#define LOADC(c) do { \
        const f4* xp = (const f4*)(xg + (c) * BK); \
        xv[0] = xp[0]; xv[1] = xp[1]; xv[2] = xp[2]; xv[3] = xp[3]; \
        const uint4* wq = (const uint4*)(wgp + (c) * BK); \
        wv[0] = wq[0]; wv[1] = wq[1]; wv[2] = wq[2]; wv[3] = wq[3]; \
    } while (0)

#define STOREC(b) do { \
        char* s_ = smem[b]; \
        _Pragma("unroll") \
        for (int g = 0; g < 2; g++) { \
            f4 a_ = xv[2*g], b_ = xv[2*g+1]; \
            ssq += a_[0]*a_[0] + a_[1]*a_[1] + a_[2]*a_[2] + a_[3]*a_[3] \
                 + b_[0]*b_[0] + b_[1]*b_[1] + b_[2]*b_[2] + b_[3]*b_[3]; \
            h8 hi_, lo_; \
            _Pragma("unroll") \
            for (int k = 0; k < 4; k++) { \
                hi_[k]   = (h16)a_[k]; lo_[k]   = (h16)(a_[k] - (float)hi_[k]); \
                hi_[k+4] = (h16)b_[k]; lo_[k+4] = (h16)(b_[k] - (float)hi_[k+4]); \
            } \
            int off_ = swz(xr, 2*xh + g); \
            *(h8*)(s_ + off_)        = hi_; \
            *(h8*)(s_ + 8192 + off_) = lo_; \
        } \
        _Pragma("unroll") \
        for (int q = 0; q < 4; q++) \
            *(uint4*)(s_ + 16384 + wp*8192 + swz(wrw, q)) = wv[q]; \
    } while (0)

#define COMPUTEC(b) do { \
        char* s_ = smem[b]; \
        h8 ah[4], al[4], bh[4], bl[4]; \
        _Pragma("unroll") \
        for (int i = 0; i < 4; i++) { \
            int off_ = swz(wr + i*16 + lrow, lslot); \
            ah[i] = *(const h8*)(s_ + off_); \
            al[i] = *(const h8*)(s_ + 8192 + off_); \
        } \
        _Pragma("unroll") \
        for (int j = 0; j < 4; j++) { \
            int off_ = swz(wc + j*16 + lrow, lslot); \
            bh[j] = *(const h8*)(s_ + 16384 + off_); \
            bl[j] = *(const h8*)(s_ + 24576 + off_); \
        } \
        _Pragma("unroll") \
        for (int i = 0; i < 4; i++) \
            _Pragma("unroll") \
            for (int j = 0; j < 4; j++) { \
                acc[i][j] = __builtin_amdgcn_mfma_f32_16x16x32_f16(ah[i], bh[j], acc[i][j], 0, 0, 0); \
                acc[i][j] = __builtin_amdgcn_mfma_f32_16x16x32_f16(ah[i], bl[j], acc[i][j], 0, 0, 0); \
                acc[i][j] = __builtin_amdgcn_mfma_f32_16x16x32_f16(al[i], bh[j], acc[i][j], 0, 0, 0); \
            } \
    } while (0)

    LOADC(0);
    STOREC(0);
    __syncthreads();
    int buf = 0;
    for (int c = 0; c < NCH; ++c) {
        if (c + 1 < NCH) LOADC(c + 1);     // issue next global loads early
        COMPUTEC(buf);                     // ds_read + MFMA hide the load latency
        if (c + 1 < NCH) STOREC(buf ^ 1);  // vmcnt wait lands here, after compute
        __syncthreads();
        buf ^= 1;
    }

    // per-token |x|^2 partial (2 staging threads per row)
    ssq += __shfl_xor(ssq, 1, 64);
    if (xh == 0) g_ssq[slice][t0 + xr] = ssq;

    // C write: col = lane&15, row = (lane>>4)*4 + reg
    #pragma unroll
    for (int i = 0; i < 4; i++)
        #pragma unroll
        for (int j = 0; j < 4; j++)
            #pragma unroll
            for (int q = 0; q < 4; q++)
                g_S[slice][t0 + wr + i*16 + lslot*4 + q][wc + j*16 + lrow] = acc[i][j][q];
}

// ---------------- kernel 3: epilogue (reduce slices, argmax, gap, softmax) ----
// grid 256 blocks x 128 threads; 64 tokens/block, 2 threads per token
__global__ __launch_bounds__(128) void k_epi() {
    __shared__ float gsm[128][65];
    const int tid = threadIdx.x;
    const int t = blockIdx.x * 64 + (tid >> 1);
    const int h = tid & 1;

    float L[64];
    {
        const float* sp = &g_S[0][t][h * 64];
        #pragma unroll
        for (int jj = 0; jj < 16; jj++) {
            f4 v = *(const f4*)(sp + jj * 4);
            L[jj*4+0] = v[0]; L[jj*4+1] = v[1]; L[jj*4+2] = v[2]; L[jj*4+3] = v[3];
        }
    }
    #pragma unroll
    for (int s = 1; s < NSPLIT; s++) {
        const float* sp = &g_S[s][t][h * 64];
        #pragma unroll
        for (int jj = 0; jj < 16; jj++) {
            f4 v = *(const f4*)(sp + jj * 4);
            L[jj*4+0] += v[0]; L[jj*4+1] += v[1]; L[jj*4+2] += v[2]; L[jj*4+3] += v[3];
        }
    }
    float n2 = g_ssq[0][t] + g_ssq[1][t] + g_ssq[2][t] + g_ssq[3][t];
    float scl = 1.0f / fmaxf(sqrtf(n2), 1e-4f);

    float m1 = -1e30f, m2 = -1e30f;
    int a1 = h * 64;
    #pragma unroll
    for (int j = 0; j < 64; j++) {
        float v = L[j] * scl;
        L[j] = v;
        if (v > m1) { m2 = m1; m1 = v; a1 = h * 64 + j; }
        else if (v > m2) m2 = v;
    }
    float m1o = __shfl_xor(m1, 1, 64);
    int   a1o = __shfl_xor(a1, 1, 64);
    float m2o = __shfl_xor(m2, 1, 64);
    float m2g = fmaxf(fmaxf(m2, m2o), fminf(m1, m1o));
    float m1g; int a1g;
    if (m1o > m1 || (m1o == m1 && a1o < a1)) { m1g = m1o; a1g = a1o; }
    else { m1g = m1; a1g = a1; }

    if (h == 0) {
        g_tte[t] = a1g;
        if (m1g - m2g < TAU) {               // near-tie -> fp32 recheck
            int ix = atomicAdd(&g_cnt, 1);
            if (ix < FIXCAP) g_flag[ix] = t;
        }
    }

    // softmax(logits/0.07) per token; accumulate per-expert column sums
    float ssum = 0.f;
    #pragma unroll
    for (int j = 0; j < 64; j++) {
        float ex = __expf((L[j] - m1g) * INV_T);
        L[j] = ex;
        ssum += ex;
    }
    ssum += __shfl_xor(ssum, 1, 64);
    float inv = 1.0f / ssum;
    #pragma unroll
    for (int j = 0; j < 64; j++) gsm[tid][j] = L[j] * inv;
    __syncthreads();

    // column sums: expert e lives in column e&63 of rows with parity e>>6
    int e = tid;
    int col = e & 63, par = e >> 6;
    float s = 0.f;
    #pragma unroll 8
    for (int m = 0; m < 64; m++) s += gsm[2 * m + par][col];
    g_me[blockIdx.x][e] = s;
}

// ---------------- kernel 4: exact fp32 recheck of near-tie tokens -------------
// One wave per flagged token. Candidates = experts within 4*TAU*||x|| of the
// approx max (ballot over the g_S partial sums); exact fp32 dot ONLY for those,
// evaluated in ascending expert order with strict > (first-index tie-break).
__global__ __launch_bounds__(64) void k_fix(const float* __restrict__ x) {
    int n = g_cnt;
    if (n > FIXCAP) n = FIXCAP;
    const int l = threadIdx.x;
    for (int i = blockIdx.x; i < n; i += gridDim.x) {
        int t = g_flag[i];
        // rebuild the 128 approx raw logits (2 per lane), same summation order as k_epi
        float v0 = g_S[0][t][l], v1 = g_S[0][t][l + 64];
        #pragma unroll
        for (int s = 1; s < NSPLIT; s++) { v0 += g_S[s][t][l]; v1 += g_S[s][t][l + 64]; }
        float m = fmaxf(v0, v1);
        #pragma unroll
        for (int o = 1; o < 64; o <<= 1) m = fmaxf(m, __shfl_xor(m, o, 64));
        float n2 = g_ssq[0][t] + g_ssq[1][t] + g_ssq[2][t] + g_ssq[3][t];
        float thr = m - 4.0f * TAU * fmaxf(sqrtf(n2), 1e-4f);   // raw-unit margin
        unsigned long long b0 = __ballot(v0 >= thr);
        unsigned long long b1 = __ballot(v1 >= thr);

        const float* xr = x + (size_t)t * D;
        float bm = -1e30f;
        int ba = 0;
        // ascending expert order: bits of b0 (e=0..63) then b1 (e=64..127)
        #pragma unroll 1
        for (int half = 0; half < 2; half++) {
            unsigned long long b = half ? b1 : b0;
            while (b) {
                int e = (__ffsll((long long)b) - 1) + half * 64;
                b &= b - 1;
                const float* wr = g_wgn + (size_t)e * D;
                float s = 0.f;
                #pragma unroll 4
                for (int c = 0; c < 16; c++) {
                    f4 xv = *(const f4*)(xr + c * 256 + l * 4);
                    f4 wv = *(const f4*)(wr + c * 256 + l * 4);
                    s = fmaf(xv[0], wv[0], s);
                    s = fmaf(xv[1], wv[1], s);
                    s = fmaf(xv[2], wv[2], s);
                    s = fmaf(xv[3], wv[3], s);
                }
                #pragma unroll
                for (int o = 1; o < 64; o <<= 1) s += __shfl_xor(s, o, 64);
                if (s > bm) { bm = s; ba = e; }
            }
        }
        if (l == 0) g_tte[t] = ba;
    }
}

// ---------------- kernel 5: per-chunk expert histograms -----------------------
__global__ __launch_bounds__(256) void k_hist() {
    __shared__ int h[NE];
    int tid = threadIdx.x;
    if (tid < NE) h[tid] = 0;
    __syncthreads();
    atomicAdd(&h[g_tte[blockIdx.x * 256 + tid]], 1);
    __syncthreads();
    if (tid < NE) g_hist[blockIdx.x][tid] = h[tid];
}

// ---------------- kernel 6: scans + l_aux + splits ----------------------------
__global__ __launch_bounds__(128) void k_scan(float* __restrict__ out) {
    __shared__ int total[NE];
    __shared__ float me[NE];
    int e = threadIdx.x;
    int run = 0;
    #pragma unroll 8
    for (int c = 0; c < NT / 256; c++) run += g_hist[c][e];
    total[e] = run;
    __syncthreads();
    int off = 0;
    for (int i = 0; i < e; i++) off += total[i];
    int p = off;
    for (int c = 0; c < NT / 256; c++) { g_pos[c][e] = p; p += g_hist[c][e]; }
    float s = 0.f;
    #pragma unroll 8
    for (int b = 0; b < 256; b++) s += g_me[b][e];
    me[e] = s;
    __syncthreads();
    if (e == 0) {
        float acc = 0.f;
        for (int i = 0; i < NE; i++)
            acc += me[i] * ((float)total[i] * (1.0f / 16384.0f) + 1e-6f);
        out[0] = acc * 128.0f;   // l_aux
    }
    out[1 + NT + e]      = (float)total[e];   // input_splits
    out[1 + NT + NE + e] = (float)total[e];   // output_splits
}

// ---------------- kernel 7: stable placement (counting sort) ------------------
__global__ __launch_bounds__(256) void k_place(float* __restrict__ out) {
    __shared__ int arr[256];
    int tid = threadIdx.x;
    int c = blockIdx.x;
    int t = c * 256 + tid;
    int e = g_tte[t];
    arr[tid] = e;
    __syncthreads();
    int rank = 0;
    for (int j = 0; j < tid; j++) rank += (arr[j] == e) ? 1 : 0;
    out[1 + g_pos[c][e] + rank] = (float)t;
}

// ---------------- launcher ----------------------------------------------------
extern "C" void kernel_launch(void* const* d_in, const int* in_sizes, int n_in,
                              void* d_out, int out_size, void* d_ws, size_t ws_size,
                              hipStream_t stream) {
    const float* x  = (const float*)d_in[0];
    const float* wg = (const float*)d_in[1];
    // d_in[2] = gating_t: sigmoid(x/temp) is monotonic -> argmax unaffected
    float* out = (float*)d_out;

    k_prep<<<NE, 256, 0, stream>>>(wg);
    k_mfma<<<128 * NSPLIT, 256, 0, stream>>>(x);
    k_epi<<<NT / 64, 128, 0, stream>>>();
    k_fix<<<256, 64, 0, stream>>>(x);
    k_hist<<<NT / 256, 256, 0, stream>>>();
    k_scan<<<1, 128, 0, stream>>>(out);
    k_place<<<NT / 256, 256, 0, stream>>>(out);
}

// Round 4
// 134.535 us; speedup vs baseline: 2.7517x; 1.2725x over previous
//
#include <hip/hip_runtime.h>
#include <math.h>

#define NT 16384
#define D 4096
#define NE 128
#define NSPLIT 4
#define KS (D / NSPLIT)   // 1024
#define BK 32
#define NCH (KS / BK)     // 32
#define BM 128
#define INV_T (1.0f / 0.07f)
#define TAU 3e-6f
#define FIXCAP 4096

typedef _Float16 h16;
typedef _Float16 h8 __attribute__((ext_vector_type(8)));
typedef _Float16 h4 __attribute__((ext_vector_type(4)));
typedef float f4 __attribute__((ext_vector_type(4)));

// ---- static device scratch (fully rewritten each call) ----
__device__ float g_S[NSPLIT][NT][NE];    // 32 MB raw-dot partials
__device__ float g_ssq[NSPLIT][NT];      // per-token |x|^2 partials
__device__ float g_wgn[NE * D];          // normalized W, fp32 (for fixup)
__device__ h16   g_whi[NE * D];          // fp16 hi split of normalized W [e][D]
__device__ h16   g_wlo[NE * D];          // fp16 lo split
__device__ int   g_tte[NT];
__device__ int   g_cnt;
__device__ int   g_flag[FIXCAP];
__device__ float g_me[256][NE];
__device__ int   g_hist[NT / 256][NE];
__device__ int   g_pos[NT / 256][NE];

#define GLL(gp, lp) __builtin_amdgcn_global_load_lds( \
    (const __attribute__((address_space(1))) void*)(gp), \
    (__attribute__((address_space(3))) void*)(lp), 16, 0, 0)

// ---------------- kernel 1: normalize W (fp32) + fp16 hi/lo split -------------
__global__ __launch_bounds__(256) void k_prep(const float* __restrict__ wg) {
    int e = blockIdx.x;
    int tid = threadIdx.x;
    if (e == 0 && tid == 0) g_cnt = 0;
    const f4* row = (const f4*)(wg + (size_t)e * D);
    float ss = 0.f;
    f4 v[4];
    #pragma unroll
    for (int c = 0; c < 4; c++) {
        v[c] = row[tid + 256 * c];
        ss += v[c][0]*v[c][0] + v[c][1]*v[c][1] + v[c][2]*v[c][2] + v[c][3]*v[c][3];
    }
    __shared__ float red[4];
    #pragma unroll
    for (int o = 32; o > 0; o >>= 1) ss += __shfl_xor(ss, o, 64);
    if ((tid & 63) == 0) red[tid >> 6] = ss;
    __syncthreads();
    float den = fmaxf(sqrtf(red[0] + red[1] + red[2] + red[3]), 1e-4f);
    #pragma unroll
    for (int c = 0; c < 4; c++) {
        size_t base = (size_t)e * D + (size_t)(tid + 256 * c) * 4;
        f4 wn;
        h4 hi, lo;
        #pragma unroll
        for (int k = 0; k < 4; k++) {
            wn[k] = v[c][k] / den;
            hi[k] = (h16)wn[k];
            lo[k] = (h16)(wn[k] - (float)hi[k]);
        }
        *(f4*)(g_wgn + base) = wn;
        *(h4*)(g_whi + base) = hi;
        *(h4*)(g_wlo + base) = lo;
    }
}

// ---------------- kernel 2: fp16x3 MFMA split-K GEMM --------------------------
// grid 512 = 128 token-blocks x 4 k-slices; 256 threads = 4 waves.
// Wave handles 32 tokens x 128 experts. A (x) goes global->regs (no LDS, no
// barrier dependency); W staged via global_load_lds into 2x16KB double buffer.
__global__ __launch_bounds__(256, 2) void k_mfma(const float* __restrict__ x) {
    __shared__ __align__(16) char wlds[2][16384];  // [buf][plane0 hi 8KB | plane1 lo 8KB]

    const int tid = threadIdx.x;
    const int bid = blockIdx.x;
    const int tb = bid & 127, slice = bid >> 7;
    const int t0 = tb * BM;
    const int kb0 = slice * KS;
    const int lane = tid & 63, wid = tid >> 6;
    const int lrow = lane & 15, lslot = lane >> 4;

    // ---- W staging geometry: slot s in [0,512) per plane: e = s>>2, ks = s&3.
    // thread stages s = tid (q0) and s = tid+256 (q1) for both planes.
    // global byte offset (within plane array): e*8192 + (kb0 + c*32 + ks*8)*2
    const char* whig = (const char*)g_whi;
    const char* wlog = (const char*)g_wlo;
    const size_t goff0 = (size_t)(tid >> 2) * 8192 + (size_t)(tid & 3) * 16 + (size_t)kb0 * 2;
    const size_t goff1 = goff0 + (size_t)64 * 8192;
    // LDS dest: wave-uniform base (HW adds lane*16): q0 -> wid*1024, q1 -> wid*1024+4096
    char* l0 = &wlds[0][wid * 1024];
    char* l1 = &wlds[1][wid * 1024];

#define STAGEW(bufp, c) do { \
        size_t co_ = (size_t)(c) * 64; \
        GLL(whig + goff0 + co_, (bufp)); \
        GLL(whig + goff1 + co_, (bufp) + 4096); \
        GLL(wlog + goff0 + co_, (bufp) + 8192); \
        GLL(wlog + goff1 + co_, (bufp) + 12288); \
    } while (0)

    // ---- x: per i-tile (i=0,1) row = t0 + wid*32 + i*16 + lrow, k = lslot*8..+8
    const float* xb0 = x + (size_t)(t0 + wid * 32 + lrow) * D + kb0 + lslot * 8;
    const float* xb1 = xb0 + (size_t)16 * D;

    f4 x0[2][2], x1[2][2];
#define LOADX(dst, c) do { \
        (dst)[0][0] = *(const f4*)(xb0 + (c) * 32); \
        (dst)[0][1] = *(const f4*)(xb0 + (c) * 32 + 4); \
        (dst)[1][0] = *(const f4*)(xb1 + (c) * 32); \
        (dst)[1][1] = *(const f4*)(xb1 + (c) * 32 + 4); \
    } while (0)

    f4 acc[2][8];
    #pragma unroll
    for (int i = 0; i < 2; i++)
        #pragma unroll
        for (int j = 0; j < 8; j++) acc[i][j] = (f4)0.0f;
    float ssq0 = 0.f, ssq1 = 0.f;

    h8 ah[2], al[2], bh[8], bl[8];

#define CONVX(src) do { \
        _Pragma("unroll") \
        for (int i = 0; i < 2; i++) { \
            _Pragma("unroll") \
            for (int e = 0; e < 4; e++) { \
                float f0_ = (src)[i][0][e], f1_ = (src)[i][1][e]; \
                if (i == 0) ssq0 += f0_ * f0_ + f1_ * f1_; \
                else        ssq1 += f0_ * f0_ + f1_ * f1_; \
                h16 h0_ = (h16)f0_, h1_ = (h16)f1_; \
                ah[i][e] = h0_; ah[i][e + 4] = h1_; \
                al[i][e] = (h16)(f0_ - (float)h0_); \
                al[i][e + 4] = (h16)(f1_ - (float)h1_); \
            } \
        } \
    } while (0)

#define DSREAD(buf) do { \
        _Pragma("unroll") \
        for (int j = 0; j < 8; j++) { \
            bh[j] = *(const h8*)(&wlds[buf][(j * 16 + lrow) * 64 + lslot * 16]); \
            bl[j] = *(const h8*)(&wlds[buf][8192 + (j * 16 + lrow) * 64 + lslot * 16]); \
        } \
    } while (0)

#define MFMAS() do { \
        _Pragma("unroll") \
        for (int i = 0; i < 2; i++) \
            _Pragma("unroll") \
            for (int j = 0; j < 8; j++) { \
                acc[i][j] = __builtin_amdgcn_mfma_f32_16x16x32_f16(ah[i], bh[j], acc[i][j], 0, 0, 0); \
                acc[i][j] = __builtin_amdgcn_mfma_f32_16x16x32_f16(ah[i], bl[j], acc[i][j], 0, 0, 0); \
                acc[i][j] = __builtin_amdgcn_mfma_f32_16x16x32_f16(al[i], bh[j], acc[i][j], 0, 0, 0); \
            } \
    } while (0)

#define BARRIER() do { \
        __builtin_amdgcn_s_barrier(); \
        __builtin_amdgcn_sched_barrier(0); \
    } while (0)

    // prologue: stage W(0), prefetch x chunks 0,1; keep x in flight (vmcnt(8))
    STAGEW(l0, 0);
    LOADX(x0, 0);
    LOADX(x1, 1);
    asm volatile("s_waitcnt vmcnt(8)" ::: "memory");
    BARRIER();

    for (int c = 0; c < NCH; c += 2) {
        // ---- even chunk: buffer 0, regs x0 ----
        STAGEW(l1, c + 1);                 // always valid (c+1 <= 31)
        CONVX(x0);
        if (c + 2 < NCH) LOADX(x0, c + 2);
        DSREAD(0);
        MFMAS();
        if (c + 2 < NCH) asm volatile("s_waitcnt vmcnt(4)" ::: "memory");
        else             asm volatile("s_waitcnt vmcnt(0)" ::: "memory");
        BARRIER();
        // ---- odd chunk: buffer 1, regs x1 ----
        if (c + 2 < NCH) STAGEW(l0, c + 2);
        CONVX(x1);
        if (c + 3 < NCH) LOADX(x1, c + 3);
        DSREAD(1);
        MFMAS();
        if (c + 2 < NCH) {                 // skip on final chunk
            asm volatile("s_waitcnt vmcnt(4)" ::: "memory");
            BARRIER();
        }
    }

    // per-token |x|^2: reduce over the 4 k-slot lanes
    ssq0 += __shfl_xor(ssq0, 16, 64); ssq0 += __shfl_xor(ssq0, 32, 64);
    ssq1 += __shfl_xor(ssq1, 16, 64); ssq1 += __shfl_xor(ssq1, 32, 64);
    if (lslot == 0) {
        g_ssq[slice][t0 + wid * 32 + lrow]      = ssq0;
        g_ssq[slice][t0 + wid * 32 + 16 + lrow] = ssq1;
    }

    // C write: row = (lane>>4)*4 + reg, col = lane&15
    #pragma unroll
    for (int i = 0; i < 2; i++)
        #pragma unroll
        for (int j = 0; j < 8; j++)
            #pragma unroll
            for (int q = 0; q < 4; q++)
                g_S[slice][t0 + wid * 32 + i * 16 + lslot * 4 + q][j * 16 + lrow] = acc[i][j][q];

#undef STAGEW
#undef LOADX
#undef CONVX
#undef DSREAD
#undef MFMAS
#undef BARRIER
}

// ---------------- kernel 3: epilogue (reduce slices, argmax, gap, softmax) ----
__global__ __launch_bounds__(128) void k_epi() {
    __shared__ float gsm[128][65];
    const int tid = threadIdx.x;
    const int t = blockIdx.x * 64 + (tid >> 1);
    const int h = tid & 1;

    float L[64];
    {
        const float* sp = &g_S[0][t][h * 64];
        #pragma unroll
        for (int jj = 0; jj < 16; jj++) {
            f4 v = *(const f4*)(sp + jj * 4);
            L[jj*4+0] = v[0]; L[jj*4+1] = v[1]; L[jj*4+2] = v[2]; L[jj*4+3] = v[3];
        }
    }
    #pragma unroll
    for (int s = 1; s < NSPLIT; s++) {
        const float* sp = &g_S[s][t][h * 64];
        #pragma unroll
        for (int jj = 0; jj < 16; jj++) {
            f4 v = *(const f4*)(sp + jj * 4);
            L[jj*4+0] += v[0]; L[jj*4+1] += v[1]; L[jj*4+2] += v[2]; L[jj*4+3] += v[3];
        }
    }
    float n2 = g_ssq[0][t] + g_ssq[1][t] + g_ssq[2][t] + g_ssq[3][t];
    float scl = 1.0f / fmaxf(sqrtf(n2), 1e-4f);

    float m1 = -1e30f, m2 = -1e30f;
    int a1 = h * 64;
    #pragma unroll
    for (int j = 0; j < 64; j++) {
        float v = L[j] * scl;
        L[j] = v;
        if (v > m1) { m2 = m1; m1 = v; a1 = h * 64 + j; }
        else if (v > m2) m2 = v;
    }
    float m1o = __shfl_xor(m1, 1, 64);
    int   a1o = __shfl_xor(a1, 1, 64);
    float m2o = __shfl_xor(m2, 1, 64);
    float m2g = fmaxf(fmaxf(m2, m2o), fminf(m1, m1o));
    float m1g; int a1g;
    if (m1o > m1 || (m1o == m1 && a1o < a1)) { m1g = m1o; a1g = a1o; }
    else { m1g = m1; a1g = a1; }

    if (h == 0) {
        g_tte[t] = a1g;
        if (m1g - m2g < TAU) {
            int ix = atomicAdd(&g_cnt, 1);
            if (ix < FIXCAP) g_flag[ix] = t;
        }
    }

    float ssum = 0.f;
    #pragma unroll
    for (int j = 0; j < 64; j++) {
        float ex = __expf((L[j] - m1g) * INV_T);
        L[j] = ex;
        ssum += ex;
    }
    ssum += __shfl_xor(ssum, 1, 64);
    float inv = 1.0f / ssum;
    #pragma unroll
    for (int j = 0; j < 64; j++) gsm[tid][j] = L[j] * inv;
    __syncthreads();

    int e = tid;
    int col = e & 63, par = e >> 6;
    float s = 0.f;
    #pragma unroll 8
    for (int m = 0; m < 64; m++) s += gsm[2 * m + par][col];
    g_me[blockIdx.x][e] = s;
}

// ---------------- kernel 4: exact fp32 recheck of near-tie tokens -------------
__global__ __launch_bounds__(64) void k_fix(const float* __restrict__ x) {
    int n = g_cnt;
    if (n > FIXCAP) n = FIXCAP;
    const int l = threadIdx.x;
    for (int i = blockIdx.x; i < n; i += gridDim.x) {
        int t = g_flag[i];
        float v0 = g_S[0][t][l], v1 = g_S[0][t][l + 64];
        #pragma unroll
        for (int s = 1; s < NSPLIT; s++) { v0 += g_S[s][t][l]; v1 += g_S[s][t][l + 64]; }
        float m = fmaxf(v0, v1);
        #pragma unroll
        for (int o = 1; o < 64; o <<= 1) m = fmaxf(m, __shfl_xor(m, o, 64));
        float n2 = g_ssq[0][t] + g_ssq[1][t] + g_ssq[2][t] + g_ssq[3][t];
        float thr = m - 4.0f * TAU * fmaxf(sqrtf(n2), 1e-4f);
        unsigned long long b0 = __ballot(v0 >= thr);
        unsigned long long b1 = __ballot(v1 >= thr);

        const float* xr = x + (size_t)t * D;
        float bm = -1e30f;
        int ba = 0;
        #pragma unroll 1
        for (int half = 0; half < 2; half++) {
            unsigned long long b = half ? b1 : b0;
            while (b) {
                int e = (__ffsll((long long)b) - 1) + half * 64;
                b &= b - 1;
                const float* wr = g_wgn + (size_t)e * D;
                float s = 0.f;
                #pragma unroll 4
                for (int c = 0; c < 16; c++) {
                    f4 xv = *(const f4*)(xr + c * 256 + l * 4);
                    f4 wv = *(const f4*)(wr + c * 256 + l * 4);
                    s = fmaf(xv[0], wv[0], s);
                    s = fmaf(xv[1], wv[1], s);
                    s = fmaf(xv[2], wv[2], s);
                    s = fmaf(xv[3], wv[3], s);
                }
                #pragma unroll
                for (int o = 1; o < 64; o <<= 1) s += __shfl_xor(s, o, 64);
                if (s > bm) { bm = s; ba = e; }
            }
        }
        if (l == 0) g_tte[t] = ba;
    }
}

// ---------------- kernel 5: per-chunk expert histograms -----------------------
__global__ __launch_bounds__(256) void k_hist() {
    __shared__ int h[NE];
    int tid = threadIdx.x;
    if (tid < NE) h[tid] = 0;
    __syncthreads();
    atomicAdd(&h[g_tte[blockIdx.x * 256 + tid]], 1);
    __syncthreads();
    if (tid < NE) g_hist[blockIdx.x][tid] = h[tid];
}

// ---------------- kernel 6: scans + l_aux + splits ----------------------------
__global__ __launch_bounds__(128) void k_scan(float* __restrict__ out) {
    __shared__ int total[NE];
    __shared__ float me[NE];
    int e = threadIdx.x;
    int run = 0;
    #pragma unroll 8
    for (int c = 0; c < NT / 256; c++) run += g_hist[c][e];
    total[e] = run;
    __syncthreads();
    int off = 0;
    for (int i = 0; i < e; i++) off += total[i];
    int p = off;
    for (int c = 0; c < NT / 256; c++) { g_pos[c][e] = p; p += g_hist[c][e]; }
    float s = 0.f;
    #pragma unroll 8
    for (int b = 0; b < 256; b++) s += g_me[b][e];
    me[e] = s;
    __syncthreads();
    if (e == 0) {
        float acc = 0.f;
        for (int i = 0; i < NE; i++)
            acc += me[i] * ((float)total[i] * (1.0f / 16384.0f) + 1e-6f);
        out[0] = acc * 128.0f;
    }
    out[1 + NT + e]      = (float)total[e];
    out[1 + NT + NE + e] = (float)total[e];
}

// ---------------- kernel 7: stable placement (counting sort) ------------------
__global__ __launch_bounds__(256) void k_place(float* __restrict__ out) {
    __shared__ int arr[256];
    int tid = threadIdx.x;
    int c = blockIdx.x;
    int t = c * 256 + tid;
    int e = g_tte[t];
    arr[tid] = e;
    __syncthreads();
    int rank = 0;
    for (int j = 0; j < tid; j++) rank += (arr[j] == e) ? 1 : 0;
    out[1 + g_pos[c][e] + rank] = (float)t;
}

// ---------------- launcher ----------------------------------------------------
extern "C" void kernel_launch(void* const* d_in, const int* in_sizes, int n_in,
                              void* d_out, int out_size, void* d_ws, size_t ws_size,
                              hipStream_t stream) {
    const float* x  = (const float*)d_in[0];
    const float* wg = (const float*)d_in[1];
    // d_in[2] = gating_t: sigmoid(x/temp) is monotonic -> argmax unaffected
    float* out = (float*)d_out;

    k_prep<<<NE, 256, 0, stream>>>(wg);
    k_mfma<<<128 * NSPLIT, 256, 0, stream>>>(x);
    k_epi<<<NT / 64, 128, 0, stream>>>();
    k_fix<<<256, 64, 0, stream>>>(x);
    k_hist<<<NT / 256, 256, 0, stream>>>();
    k_scan<<<1, 128, 0, stream>>>(out);
    k_place<<<NT / 256, 256, 0, stream>>>(out);
}